// Round 1
// baseline (1149.422 us; speedup 1.0000x reference)
//
#include <hip/hip_runtime.h>
#include <math.h>

#define HID 128
#define INSZ 9

__global__ void zero_f32(float* __restrict__ p, int n) {
    int i = blockIdx.x * blockDim.x + threadIdx.x;
    if (i < n) p[i] = 0.0f;
}

__launch_bounds__(256, 2)
__global__ void gnn_edge_kernel(
    const float* __restrict__ pos, const float* __restrict__ vel,
    const float* __restrict__ a, const float* __restrict__ vnorm,
    const float* __restrict__ w0, const float* __restrict__ b0,
    const float* __restrict__ w1, const float* __restrict__ b1,
    const float* __restrict__ w2, const float* __restrict__ b2,
    const float* __restrict__ w3, const float* __restrict__ b3,
    const float* __restrict__ w4, const float* __restrict__ b4,
    const int* __restrict__ ei, const int* __restrict__ did,
    float* __restrict__ out, int nNodes, int nEdges)
{
    // LDS: H activations 64x132 (pad), W^T staged in k-halves with XOR swizzle
    __shared__ __align__(16) float Hs[64 * 132];   // 33792 B
    __shared__ __align__(16) float Ws[128 * 68];   // 34816 B
    __shared__ float Bs[128];

    const int tid = threadIdx.x;
    const int jg  = tid & 15;   // 16 j-groups of 8 output cols
    const int eg  = tid >> 4;   // 16 e-groups of 4 edge rows
    const int e0  = blockIdx.x * 64;

    // ---- phase A: gather edge features into Hs rows ----
    if (tid < 64) {
        int e = e0 + tid;
        int dsti = 0, srci = 0;
        if (e < nEdges) { dsti = ei[e]; srci = ei[nEdges + e]; }
        float2 pd = ((const float2*)pos)[dsti];
        float2 ps = ((const float2*)pos)[srci];
        float2 vd = ((const float2*)vel)[dsti];
        float2 vs = ((const float2*)vel)[srci];
        const float* emb = a + (size_t)did[0] * (size_t)(nNodes * 2);
        float2 ed2 = ((const float2*)emb)[dsti];
        float invn = 1.0f / vnorm[0];
        float dx = (ps.x - pd.x) / 0.1f;
        float dy = (ps.y - pd.y) / 0.1f;
        float r  = sqrtf(dx * dx + dy * dy);
        float* hrow = &Hs[tid * 132];
        hrow[0] = dx; hrow[1] = dy; hrow[2] = r;
        hrow[3] = vd.x * invn; hrow[4] = vd.y * invn;
        hrow[5] = vs.x * invn; hrow[6] = vs.y * invn;
        hrow[7] = ed2.x; hrow[8] = ed2.y;
    }
    // stage W0^T (stride 13, tiny) + b0
    if (tid < 128) {
        int j = tid;
        #pragma unroll
        for (int k = 0; k < INSZ; ++k) Ws[j * 13 + k] = w0[k * HID + j];
        Bs[j] = b0[j];
    }
    __syncthreads();

    float acc[4][8];

    // ---- layer 0: 9 -> 128 ----
    #pragma unroll
    for (int e_ = 0; e_ < 4; ++e_)
        #pragma unroll
        for (int ji = 0; ji < 8; ++ji) acc[e_][ji] = Bs[8 * jg + ji];
    #pragma unroll
    for (int k = 0; k < INSZ; ++k) {
        float h[4];
        #pragma unroll
        for (int e_ = 0; e_ < 4; ++e_) h[e_] = Hs[(4 * eg + e_) * 132 + k];
        #pragma unroll
        for (int ji = 0; ji < 8; ++ji) {
            float w = Ws[(8 * jg + ji) * 13 + k];
            #pragma unroll
            for (int e_ = 0; e_ < 4; ++e_) acc[e_][ji] += h[e_] * w;
        }
    }
    #pragma unroll
    for (int e_ = 0; e_ < 4; ++e_)
        #pragma unroll
        for (int ji = 0; ji < 8; ++ji) acc[e_][ji] = fmaxf(acc[e_][ji], 0.0f);
    __syncthreads();
    #pragma unroll
    for (int e_ = 0; e_ < 4; ++e_) {
        float4 v0 = make_float4(acc[e_][0], acc[e_][1], acc[e_][2], acc[e_][3]);
        float4 v1 = make_float4(acc[e_][4], acc[e_][5], acc[e_][6], acc[e_][7]);
        *(float4*)&Hs[(4 * eg + e_) * 132 + 8 * jg]     = v0;
        *(float4*)&Hs[(4 * eg + e_) * 132 + 8 * jg + 4] = v1;
    }

    // ---- layers 1..3: 128 -> 128, staged in two k-halves ----
    auto stage_half = [&](const float* wl, int kh) {
        #pragma unroll
        for (int it = 0; it < 8; ++it) {
            int idx = tid + it * 256;
            int j = idx & 127;
            int c = idx >> 7;              // 0..15 chunk within half
            int k0 = kh * 64 + c * 4;
            float4 v;
            v.x = wl[(k0 + 0) * HID + j];
            v.y = wl[(k0 + 1) * HID + j];
            v.z = wl[(k0 + 2) * HID + j];
            v.w = wl[(k0 + 3) * HID + j];
            *(float4*)&Ws[j * 68 + ((c ^ ((j >> 3) & 7)) << 2)] = v;
        }
    };
    auto fma_half = [&](int kh) {
        #pragma unroll 4
        for (int cc = 0; cc < 16; ++cc) {
            float4 h[4];
            #pragma unroll
            for (int e_ = 0; e_ < 4; ++e_)
                h[e_] = *(const float4*)&Hs[(4 * eg + e_) * 132 + kh * 64 + cc * 4];
            #pragma unroll
            for (int ji = 0; ji < 8; ++ji) {
                float4 w = *(const float4*)&Ws[(8 * jg + ji) * 68 + ((cc ^ (jg & 7)) << 2)];
                #pragma unroll
                for (int e_ = 0; e_ < 4; ++e_) {
                    acc[e_][ji] += h[e_].x * w.x;
                    acc[e_][ji] += h[e_].y * w.y;
                    acc[e_][ji] += h[e_].z * w.z;
                    acc[e_][ji] += h[e_].w * w.w;
                }
            }
        }
    };

    const float* WL[3] = {w1, w2, w3};
    const float* BL[3] = {b1, b2, b3};
    #pragma unroll
    for (int l = 0; l < 3; ++l) {
        stage_half(WL[l], 0);
        if (tid < 128) Bs[tid] = BL[l][tid];
        __syncthreads();
        #pragma unroll
        for (int e_ = 0; e_ < 4; ++e_)
            #pragma unroll
            for (int ji = 0; ji < 8; ++ji) acc[e_][ji] = Bs[8 * jg + ji];
        fma_half(0);
        __syncthreads();
        stage_half(WL[l], 1);
        __syncthreads();
        fma_half(1);
        #pragma unroll
        for (int e_ = 0; e_ < 4; ++e_)
            #pragma unroll
            for (int ji = 0; ji < 8; ++ji) acc[e_][ji] = fmaxf(acc[e_][ji], 0.0f);
        __syncthreads();
        #pragma unroll
        for (int e_ = 0; e_ < 4; ++e_) {
            float4 v0 = make_float4(acc[e_][0], acc[e_][1], acc[e_][2], acc[e_][3]);
            float4 v1 = make_float4(acc[e_][4], acc[e_][5], acc[e_][6], acc[e_][7]);
            *(float4*)&Hs[(4 * eg + e_) * 132 + 8 * jg]     = v0;
            *(float4*)&Hs[(4 * eg + e_) * 132 + 8 * jg + 4] = v1;
        }
    }

    // ---- final layer: 128 -> 2, then atomic segment-sum ----
    // stage w4 (128x2 row-major = 256 floats, linear) + b4
    Ws[tid] = w4[tid];
    if (tid < 2) Bs[tid] = b4[tid];
    __syncthreads();
    if (tid < 64) {
        int e = e0 + tid;
        if (e < nEdges) {
            float acc0 = Bs[0], acc1 = Bs[1];
            const float* hrow = &Hs[tid * 132];
            #pragma unroll
            for (int k = 0; k < HID; k += 4) {
                float4 h  = *(const float4*)&hrow[k];
                float4 wa = *(const float4*)&Ws[2 * k];      // w4[k][0..1], w4[k+1][0..1]
                float4 wb = *(const float4*)&Ws[2 * k + 4];  // w4[k+2][0..1], w4[k+3][0..1]
                acc0 += h.x * wa.x + h.y * wa.z + h.z * wb.x + h.w * wb.z;
                acc1 += h.x * wa.y + h.y * wa.w + h.z * wb.y + h.w * wb.w;
            }
            int dsti = ei[e];
            atomicAdd(&out[2 * dsti],     acc0);
            atomicAdd(&out[2 * dsti + 1], acc1);
        }
    }
}

extern "C" void kernel_launch(void* const* d_in, const int* in_sizes, int n_in,
                              void* d_out, int out_size, void* d_ws, size_t ws_size,
                              hipStream_t stream) {
    const float* pos   = (const float*)d_in[0];
    const float* vel   = (const float*)d_in[1];
    const float* a     = (const float*)d_in[2];
    const float* vnorm = (const float*)d_in[3];
    const float* w0    = (const float*)d_in[4];
    const float* b0    = (const float*)d_in[5];
    const float* w1    = (const float*)d_in[6];
    const float* b1    = (const float*)d_in[7];
    const float* w2    = (const float*)d_in[8];
    const float* b2    = (const float*)d_in[9];
    const float* w3    = (const float*)d_in[10];
    const float* b3    = (const float*)d_in[11];
    const float* w4    = (const float*)d_in[12];
    const float* b4    = (const float*)d_in[13];
    const int*   ei    = (const int*)d_in[14];
    const int*   did   = (const int*)d_in[15];
    float* out = (float*)d_out;

    int nEdges = in_sizes[14] / 2;   // 800000
    int nNodes = in_sizes[0] / 2;    // 50000

    hipLaunchKernelGGL(zero_f32, dim3((out_size + 255) / 256), dim3(256), 0, stream,
                       out, out_size);
    int ntiles = (nEdges + 63) / 64;
    hipLaunchKernelGGL(gnn_edge_kernel, dim3(ntiles), dim3(256), 0, stream,
                       pos, vel, a, vnorm, w0, b0, w1, b1, w2, b2, w3, b3, w4, b4,
                       ei, did, out, nNodes, nEdges);
}

// Round 2
// 309.613 us; speedup vs baseline: 3.7124x; 3.7124x over previous
//
#include <hip/hip_runtime.h>
#include <math.h>

typedef _Float16 f16;
typedef f16 f16x8 __attribute__((ext_vector_type(8)));
typedef f16 f16x4 __attribute__((ext_vector_type(4)));
typedef float f32x16 __attribute__((ext_vector_type(16)));

// ws layout (f16 units):
//  (l,h) block at (l*2+h)*16384 : hi[8192] then lo[8192]
//     within hi/lo: f*64 + (c ^ (f&7))*8 + i   (c = kk>>3, kk = k&63, i = k&7)
//  W0T at 98304: hi f*16+k (k 0..15, zero-padded past 9), lo at +2048
#define WS_W0 98304
#define WS_TOTAL_F16 102400

__global__ void zero_f32(float* __restrict__ p, int n) {
    int i = blockIdx.x * blockDim.x + threadIdx.x;
    if (i < n) p[i] = 0.0f;
}

__global__ void prep_weights(const float* __restrict__ w1, const float* __restrict__ w2,
                             const float* __restrict__ w3, const float* __restrict__ w0,
                             f16* __restrict__ ws) {
    int t = blockIdx.x * 256 + threadIdx.x;
    if (t < 49152) {
        int L = t >> 14;
        int r = t & 16383;
        int k = r >> 7, f = r & 127;
        const float* w = (L == 0) ? w1 : (L == 1) ? w2 : w3;
        float v = w[k * 128 + f];
        f16 h = (f16)v;
        f16 lo = (f16)(v - (float)h);
        int half = k >> 6, kk = k & 63;
        int pos = f * 64 + ((kk >> 3) ^ (f & 7)) * 8 + (kk & 7);
        int base = (L * 2 + half) * 16384;
        ws[base + pos] = h;
        ws[base + 8192 + pos] = lo;
    } else if (t < 51200) {
        int r = t - 49152;
        int k = r >> 7, f = r & 127;
        float v = (k < 9) ? w0[k * 128 + f] : 0.0f;
        f16 h = (f16)v;
        f16 lo = (f16)(v - (float)h);
        ws[WS_W0 + f * 16 + k] = h;
        ws[WS_W0 + 2048 + f * 16 + k] = lo;
    }
}

__launch_bounds__(256, 2)
__global__ void gnn_mfma(const float* __restrict__ pos, const float* __restrict__ vel,
                         const float* __restrict__ a, const float* __restrict__ vnorm,
                         const float* __restrict__ b0, const float* __restrict__ b1,
                         const float* __restrict__ b2, const float* __restrict__ b3,
                         const float* __restrict__ w4, const float* __restrict__ b4,
                         const int* __restrict__ ei, const int* __restrict__ did,
                         const f16* __restrict__ ws, float* __restrict__ out,
                         int nNodes, int nEdges)
{
    __shared__ __align__(16) f16 Ahi[64 * 128];   // 16 KB, chunk-swizzled (c ^ (e&7))
    __shared__ __align__(16) f16 Alo[64 * 128];   // 16 KB
    __shared__ __align__(16) f16 Wbuf[16384];     // 32 KB: hi[8192], lo[8192]
    __shared__ float Bias[512];                   // b0,b1,b2,b3
    __shared__ float W4s[256];

    const int tid = threadIdx.x;
    const int lane = tid & 63;
    const int wid = tid >> 6;
    const int eg = wid & 1, fg = wid >> 1;
    const int g = lane >> 5;
    const int ln = lane & 31;
    const int el = 32 * eg + ln;          // this lane's edge row (B-frag col)
    const int e0 = blockIdx.x * 64;

    if (tid < 128) {
        Bias[tid] = b0[tid]; Bias[128 + tid] = b1[tid];
        Bias[256 + tid] = b2[tid]; Bias[384 + tid] = b3[tid];
    }
    if (tid >= 128 && tid < 192) ((float4*)W4s)[tid - 128] = ((const float4*)w4)[tid - 128];

    // ---- gather: 9 features -> A0 (k 0..15, zero padded), split hi/lo ----
    if (tid < 64) {
        int e = e0 + tid;
        int d = 0, s = 0;
        if (e < nEdges) { d = ei[e]; s = ei[nEdges + e]; }
        float2 pd = ((const float2*)pos)[d];
        float2 ps = ((const float2*)pos)[s];
        float2 vd = ((const float2*)vel)[d];
        float2 vs = ((const float2*)vel)[s];
        const float2* emb = (const float2*)(a + (size_t)did[0] * (size_t)nNodes * 2);
        float2 ae = emb[d];
        float invn = 1.0f / vnorm[0];
        float fx[9];
        fx[0] = (ps.x - pd.x) / 0.1f;
        fx[1] = (ps.y - pd.y) / 0.1f;
        fx[2] = sqrtf(fx[0] * fx[0] + fx[1] * fx[1]);
        fx[3] = vd.x * invn; fx[4] = vd.y * invn;
        fx[5] = vs.x * invn; fx[6] = vs.y * invn;
        fx[7] = ae.x; fx[8] = ae.y;
        f16x8 h0, l0, h1, l1;
        #pragma unroll
        for (int i = 0; i < 8; ++i) {
            f16 h = (f16)fx[i];
            h0[i] = h; l0[i] = (f16)(fx[i] - (float)h);
            h1[i] = (f16)0; l1[i] = (f16)0;
        }
        f16 h8 = (f16)fx[8];
        h1[0] = h8; l1[0] = (f16)(fx[8] - (float)h8);
        int er = tid;
        *(f16x8*)&Ahi[er * 128 + 8 * (0 ^ (er & 7))] = h0;
        *(f16x8*)&Alo[er * 128 + 8 * (0 ^ (er & 7))] = l0;
        *(f16x8*)&Ahi[er * 128 + 8 * (1 ^ (er & 7))] = h1;
        *(f16x8*)&Alo[er * 128 + 8 * (1 ^ (er & 7))] = l1;
    }
    __syncthreads();

    const f16x8* wsv = (const f16x8*)ws;
    f16x8 st[8];

    f32x16 acc[2];

    // prefetch (w1, half0) into regs
    #pragma unroll
    for (int i = 0; i < 8; ++i) st[i] = wsv[0 * 2048 + tid + i * 256];

    // ---- layer 0: K=16, W0 frags straight from global (L1/L2-resident) ----
    #pragma unroll
    for (int ft = 0; ft < 2; ++ft)
        #pragma unroll
        for (int r = 0; r < 16; ++r)
            acc[ft][r] = Bias[0 + 64 * fg + 32 * ft + (r & 3) + 8 * (r >> 2) + 4 * g];
    {
        int ad = el * 128 + 8 * (g ^ (el & 7));
        f16x8 bhi = *(const f16x8*)&Ahi[ad];
        f16x8 blo = *(const f16x8*)&Alo[ad];
        const f16x8* w0h = (const f16x8*)(ws + WS_W0);
        const f16x8* w0l = (const f16x8*)(ws + WS_W0 + 2048);
        #pragma unroll
        for (int ft = 0; ft < 2; ++ft) {
            int f = 64 * fg + 32 * ft + ln;
            f16x8 whi = w0h[f * 2 + g];
            f16x8 wlo = w0l[f * 2 + g];
            acc[ft] = __builtin_amdgcn_mfma_f32_32x32x16_f16(whi, bhi, acc[ft], 0, 0, 0);
            acc[ft] = __builtin_amdgcn_mfma_f32_32x32x16_f16(whi, blo, acc[ft], 0, 0, 0);
            acc[ft] = __builtin_amdgcn_mfma_f32_32x32x16_f16(wlo, bhi, acc[ft], 0, 0, 0);
        }
    }
    __syncthreads();
    // writeA(layer0) + commit stage(w1,h0)
    #pragma unroll
    for (int ft = 0; ft < 2; ++ft)
        #pragma unroll
        for (int j = 0; j < 4; ++j) {
            f16x4 hv, lv;
            #pragma unroll
            for (int r = 0; r < 4; ++r) {
                float v = fmaxf(acc[ft][4 * j + r], 0.0f);
                f16 h = (f16)v;
                hv[r] = h; lv[r] = (f16)(v - (float)h);
            }
            int c = 8 * fg + 4 * ft + j;
            int ad = el * 128 + 8 * (c ^ (el & 7)) + 4 * g;
            *(f16x4*)&Ahi[ad] = hv;
            *(f16x4*)&Alo[ad] = lv;
        }
    {
        f16x8* wb = (f16x8*)Wbuf;
        #pragma unroll
        for (int i = 0; i < 8; ++i) wb[tid + i * 256] = st[i];
    }
    __syncthreads();

    // ---- mid layers l=0..2 (w1,w2,w3), K=128 in two staged halves ----
    #pragma unroll 1
    for (int l = 0; l < 3; ++l) {
        #pragma unroll
        for (int ft = 0; ft < 2; ++ft)
            #pragma unroll
            for (int r = 0; r < 16; ++r)
                acc[ft][r] = Bias[128 * (l + 1) + 64 * fg + 32 * ft + (r & 3) + 8 * (r >> 2) + 4 * g];

        // prefetch (l, half1)
        #pragma unroll
        for (int i = 0; i < 8; ++i) st[i] = wsv[(l * 2 + 1) * 2048 + tid + i * 256];

        #pragma unroll
        for (int ks = 0; ks < 4; ++ks) {
            int ad = el * 128 + 8 * ((2 * ks + g) ^ (el & 7));
            f16x8 bhi = *(const f16x8*)&Ahi[ad];
            f16x8 blo = *(const f16x8*)&Alo[ad];
            #pragma unroll
            for (int ft = 0; ft < 2; ++ft) {
                int f = 64 * fg + 32 * ft + ln;
                int wa = f * 64 + 8 * ((2 * ks + g) ^ (f & 7));
                f16x8 whi = *(const f16x8*)&Wbuf[wa];
                f16x8 wlo = *(const f16x8*)&Wbuf[8192 + wa];
                acc[ft] = __builtin_amdgcn_mfma_f32_32x32x16_f16(whi, bhi, acc[ft], 0, 0, 0);
                acc[ft] = __builtin_amdgcn_mfma_f32_32x32x16_f16(whi, blo, acc[ft], 0, 0, 0);
                acc[ft] = __builtin_amdgcn_mfma_f32_32x32x16_f16(wlo, bhi, acc[ft], 0, 0, 0);
            }
        }
        __syncthreads();
        {
            f16x8* wb = (f16x8*)Wbuf;
            #pragma unroll
            for (int i = 0; i < 8; ++i) wb[tid + i * 256] = st[i];
        }
        __syncthreads();
        // prefetch (l+1, half0)
        if (l < 2) {
            #pragma unroll
            for (int i = 0; i < 8; ++i) st[i] = wsv[((l + 1) * 2) * 2048 + tid + i * 256];
        }
        #pragma unroll
        for (int ks = 4; ks < 8; ++ks) {
            int ksh = ks - 4;
            int ad = el * 128 + 8 * ((2 * ks + g) ^ (el & 7));
            f16x8 bhi = *(const f16x8*)&Ahi[ad];
            f16x8 blo = *(const f16x8*)&Alo[ad];
            #pragma unroll
            for (int ft = 0; ft < 2; ++ft) {
                int f = 64 * fg + 32 * ft + ln;
                int wa = f * 64 + 8 * ((2 * ksh + g) ^ (f & 7));
                f16x8 whi = *(const f16x8*)&Wbuf[wa];
                f16x8 wlo = *(const f16x8*)&Wbuf[8192 + wa];
                acc[ft] = __builtin_amdgcn_mfma_f32_32x32x16_f16(whi, bhi, acc[ft], 0, 0, 0);
                acc[ft] = __builtin_amdgcn_mfma_f32_32x32x16_f16(whi, blo, acc[ft], 0, 0, 0);
                acc[ft] = __builtin_amdgcn_mfma_f32_32x32x16_f16(wlo, bhi, acc[ft], 0, 0, 0);
            }
        }
        __syncthreads();
        // ReLU + split + in-place write of next activations
        #pragma unroll
        for (int ft = 0; ft < 2; ++ft)
            #pragma unroll
            for (int j = 0; j < 4; ++j) {
                f16x4 hv, lv;
                #pragma unroll
                for (int r = 0; r < 4; ++r) {
                    float v = fmaxf(acc[ft][4 * j + r], 0.0f);
                    f16 h = (f16)v;
                    hv[r] = h; lv[r] = (f16)(v - (float)h);
                }
                int c = 8 * fg + 4 * ft + j;
                int ad = el * 128 + 8 * (c ^ (el & 7)) + 4 * g;
                *(f16x4*)&Ahi[ad] = hv;
                *(f16x4*)&Alo[ad] = lv;
            }
        if (l < 2) {
            f16x8* wb = (f16x8*)Wbuf;
            #pragma unroll
            for (int i = 0; i < 8; ++i) wb[tid + i * 256] = st[i];
        }
        __syncthreads();
    }

    // ---- final layer 128 -> 2, 4 lanes per edge, atomic segment-sum ----
    {
        int e = tid >> 2, q = tid & 3;
        float y0 = 0.0f, y1 = 0.0f;
        #pragma unroll
        for (int cc = 0; cc < 4; ++cc) {
            int c = 4 * q + cc;
            int ad = e * 128 + 8 * (c ^ (e & 7));
            f16x8 hv = *(const f16x8*)&Ahi[ad];
            f16x8 lv = *(const f16x8*)&Alo[ad];
            #pragma unroll
            for (int i = 0; i < 8; ++i) {
                float x = (float)hv[i] + (float)lv[i];
                int k = 8 * c + i;
                y0 += x * W4s[2 * k];
                y1 += x * W4s[2 * k + 1];
            }
        }
        y0 += __shfl_xor(y0, 1); y0 += __shfl_xor(y0, 2);
        y1 += __shfl_xor(y1, 1); y1 += __shfl_xor(y1, 2);
        int eG = e0 + e;
        if (q == 0 && eG < nEdges) {
            int d = ei[eG];
            atomicAdd(&out[2 * d],     y0 + b4[0]);
            atomicAdd(&out[2 * d + 1], y1 + b4[1]);
        }
    }
}

extern "C" void kernel_launch(void* const* d_in, const int* in_sizes, int n_in,
                              void* d_out, int out_size, void* d_ws, size_t ws_size,
                              hipStream_t stream) {
    const float* pos   = (const float*)d_in[0];
    const float* vel   = (const float*)d_in[1];
    const float* a     = (const float*)d_in[2];
    const float* vnorm = (const float*)d_in[3];
    const float* w0    = (const float*)d_in[4];
    const float* b0    = (const float*)d_in[5];
    const float* w1    = (const float*)d_in[6];
    const float* b1    = (const float*)d_in[7];
    const float* w2    = (const float*)d_in[8];
    const float* b2    = (const float*)d_in[9];
    const float* w3    = (const float*)d_in[10];
    const float* b3    = (const float*)d_in[11];
    const float* w4    = (const float*)d_in[12];
    const float* b4    = (const float*)d_in[13];
    const int*   ei    = (const int*)d_in[14];
    const int*   did   = (const int*)d_in[15];
    float* out = (float*)d_out;
    f16* ws = (f16*)d_ws;

    int nEdges = in_sizes[14] / 2;   // 800000
    int nNodes = in_sizes[0] / 2;    // 50000

    hipLaunchKernelGGL(zero_f32, dim3((out_size + 255) / 256), dim3(256), 0, stream,
                       out, out_size);
    hipLaunchKernelGGL(prep_weights, dim3(200), dim3(256), 0, stream, w1, w2, w3, w0, ws);
    int ntiles = (nEdges + 63) / 64;
    hipLaunchKernelGGL(gnn_mfma, dim3(ntiles), dim3(256), 0, stream,
                       pos, vel, a, vnorm, b0, b1, b2, b3, w4, b4, ei, did, ws, out,
                       nNodes, nEdges);
}

// Round 3
// 214.816 us; speedup vs baseline: 5.3507x; 1.4413x over previous
//
#include <hip/hip_runtime.h>
#include <math.h>

typedef _Float16 f16;
typedef f16 f16x8 __attribute__((ext_vector_type(8)));
typedef f16 f16x4 __attribute__((ext_vector_type(4)));
typedef float f32x16 __attribute__((ext_vector_type(16)));

// ws layout (f16 units):
//  mid W (w1,w2,w3) as per-wave A-frags, single f16:
//    flat = (((l*2+fg)*8+ks)*2+ft)*512 + (32*g+ln)*8 + i
//    (f = 64*fg+32*ft+ln, k = 16*ks+8*g+i)
//  W0 frags at 49152: flat = 49152 + ((fg*2+ft)*2+g)*256 + ln*8 + i (k<16, pad 0)
#define WS_W0 49152

__global__ void zero_f32(float* __restrict__ p, int n) {
    int i = blockIdx.x * blockDim.x + threadIdx.x;
    if (i < n) p[i] = 0.0f;
}

__global__ void prep_weights(const float* __restrict__ w1, const float* __restrict__ w2,
                             const float* __restrict__ w3, const float* __restrict__ w0,
                             f16* __restrict__ ws) {
    int t = blockIdx.x * 256 + threadIdx.x;
    if (t < 49152) {
        int l = t >> 14;
        int r = t & 16383;
        int k = r >> 7, f = r & 127;
        const float* w = (l == 0) ? w1 : (l == 1) ? w2 : w3;
        float v = w[k * 128 + f];
        int fg = f >> 6, ft = (f >> 5) & 1, ln = f & 31;
        int ks = k >> 4, g = (k >> 3) & 1, i = k & 7;
        ws[(((l * 2 + fg) * 8 + ks) * 2 + ft) * 512 + (32 * g + ln) * 8 + i] = (f16)v;
    } else if (t < 51200) {
        int r = t - 49152;
        int k = r >> 7, f = r & 127;   // k 0..15
        float v = (k < 9) ? w0[k * 128 + f] : 0.0f;
        int fg = f >> 6, ft = (f >> 5) & 1, ln = f & 31;
        int g = (k >> 3) & 1, i = k & 7;
        ws[WS_W0 + ((fg * 2 + ft) * 2 + g) * 256 + ln * 8 + i] = (f16)v;
    }
}

__launch_bounds__(256, 2)
__global__ void gnn_mfma(const float* __restrict__ pos, const float* __restrict__ vel,
                         const float* __restrict__ a, const float* __restrict__ vnorm,
                         const float* __restrict__ b0, const float* __restrict__ b1,
                         const float* __restrict__ b2, const float* __restrict__ b3,
                         const float* __restrict__ w4, const float* __restrict__ b4,
                         const int* __restrict__ ei, const int* __restrict__ did,
                         const f16* __restrict__ ws, float* __restrict__ out,
                         int nNodes, int nEdges)
{
    __shared__ __align__(16) f16 Ha0[8192], La0[8192], Ha1[8192], La1[8192]; // 4x16KB
    __shared__ float Bias[512];
    __shared__ float W4r[4 * 260];   // 4 q-replicas, stride 260 (bank-offset 4q)

    const int tid = threadIdx.x;
    const int lane = tid & 63;
    const int wid = tid >> 6;
    const int eg = wid & 1, fg = wid >> 1;
    const int g = lane >> 5, ln = lane & 31;
    const int el = 32 * eg + ln;
    const int e0 = blockIdx.x * 64;

    const f16x8* wsv = (const f16x8*)ws;
    f16x8 Wa[16], Wb[16];

    // prefetch w1 -> Wa (used at L1)
    #pragma unroll
    for (int ks = 0; ks < 8; ++ks)
        #pragma unroll
        for (int ft = 0; ft < 2; ++ft)
            Wa[ks * 2 + ft] = wsv[(((0 * 2 + fg) * 8 + ks) * 2 + ft) * 64 + lane];

    // W0 frags
    f16x8 w00 = wsv[WS_W0 / 8 + ((fg * 2 + 0) * 2 + g) * 32 + ln];
    f16x8 w01 = wsv[WS_W0 / 8 + ((fg * 2 + 1) * 2 + g) * 32 + ln];

    // stage biases + replicated w4
    if (tid < 128) {
        Bias[tid] = b0[tid]; Bias[128 + tid] = b1[tid];
        Bias[256 + tid] = b2[tid]; Bias[384 + tid] = b3[tid];
    }
    {
        int q = tid >> 6, r = tid & 63;
        #pragma unroll
        for (int it = 0; it < 4; ++it)
            W4r[q * 260 + r + 64 * it] = w4[r + 64 * it];
    }

    // gather: 9 features -> Ha0/La0 rows (chunks 0,1 = k 0..15, pad 0)
    if (tid < 64) {
        int e = e0 + tid;
        int d = 0, s = 0;
        if (e < nEdges) { d = ei[e]; s = ei[nEdges + e]; }
        float2 pd = ((const float2*)pos)[d];
        float2 ps = ((const float2*)pos)[s];
        float2 vd = ((const float2*)vel)[d];
        float2 vs = ((const float2*)vel)[s];
        const float2* emb = (const float2*)(a + (size_t)did[0] * (size_t)nNodes * 2);
        float2 ae = emb[d];
        float invn = 1.0f / vnorm[0];
        float fx[9];
        fx[0] = (ps.x - pd.x) / 0.1f;
        fx[1] = (ps.y - pd.y) / 0.1f;
        fx[2] = sqrtf(fx[0] * fx[0] + fx[1] * fx[1]);
        fx[3] = vd.x * invn; fx[4] = vd.y * invn;
        fx[5] = vs.x * invn; fx[6] = vs.y * invn;
        fx[7] = ae.x; fx[8] = ae.y;
        f16x8 h0, l0, h1, l1;
        #pragma unroll
        for (int i = 0; i < 8; ++i) {
            f16 h = (f16)fx[i];
            h0[i] = h; l0[i] = (f16)(fx[i] - (float)h);
            h1[i] = (f16)0; l1[i] = (f16)0;
        }
        f16 h8 = (f16)fx[8];
        h1[0] = h8; l1[0] = (f16)(fx[8] - (float)h8);
        int er = tid;
        *(f16x8*)&Ha0[er * 128 + 8 * (0 ^ (er & 7))] = h0;
        *(f16x8*)&La0[er * 128 + 8 * (0 ^ (er & 7))] = l0;
        *(f16x8*)&Ha0[er * 128 + 8 * (1 ^ (er & 7))] = h1;
        *(f16x8*)&La0[er * 128 + 8 * (1 ^ (er & 7))] = l1;
    }
    __syncthreads();

    // ReLU + hi/lo split + swizzled write of next activations
    auto writeback = [&](f16* Nhi, f16* Nlo, const f32x16& A0, const f32x16& A1) {
        #pragma unroll
        for (int ft = 0; ft < 2; ++ft) {
            #pragma unroll
            for (int j = 0; j < 4; ++j) {
                f16x4 hv, lv;
                #pragma unroll
                for (int r = 0; r < 4; ++r) {
                    float v = fmaxf((ft ? A1 : A0)[4 * j + r], 0.0f);
                    f16 h = (f16)v;
                    hv[r] = h; lv[r] = (f16)(v - (float)h);
                }
                int c = 8 * fg + 4 * ft + j;
                int ad = el * 128 + 8 * (c ^ (el & 7)) + 4 * g;
                *(f16x4*)&Nhi[ad] = hv;
                *(f16x4*)&Nlo[ad] = lv;
            }
        }
    };

    // ---- layer 0: K=16 ----
    {
        // prefetch w2 -> Wb (used at L2)
        #pragma unroll
        for (int ks = 0; ks < 8; ++ks)
            #pragma unroll
            for (int ft = 0; ft < 2; ++ft)
                Wb[ks * 2 + ft] = wsv[(((1 * 2 + fg) * 8 + ks) * 2 + ft) * 64 + lane];

        f32x16 a0, a1;
        #pragma unroll
        for (int r = 0; r < 16; ++r) {
            a0[r] = Bias[64 * fg + (r & 3) + 8 * (r >> 2) + 4 * g];
            a1[r] = Bias[64 * fg + 32 + (r & 3) + 8 * (r >> 2) + 4 * g];
        }
        int ad = el * 128 + 8 * (g ^ (el & 7));
        f16x8 bhi = *(const f16x8*)&Ha0[ad];
        f16x8 blo = *(const f16x8*)&La0[ad];
        a0 = __builtin_amdgcn_mfma_f32_32x32x16_f16(w00, bhi, a0, 0, 0, 0);
        a1 = __builtin_amdgcn_mfma_f32_32x32x16_f16(w01, bhi, a1, 0, 0, 0);
        a0 = __builtin_amdgcn_mfma_f32_32x32x16_f16(w00, blo, a0, 0, 0, 0);
        a1 = __builtin_amdgcn_mfma_f32_32x32x16_f16(w01, blo, a1, 0, 0, 0);
        writeback(Ha1, La1, a0, a1);
    }
    __syncthreads();

    // ---- mid layer: K=128, W from registers, B hi/lo from LDS ----
    auto midlayer = [&](const f16x8* W, int boff, const f16* Chi, const f16* Clo,
                        f16* Nhi, f16* Nlo) {
        f32x16 a0, a1;
        #pragma unroll
        for (int r = 0; r < 16; ++r) {
            a0[r] = Bias[boff + 64 * fg + (r & 3) + 8 * (r >> 2) + 4 * g];
            a1[r] = Bias[boff + 64 * fg + 32 + (r & 3) + 8 * (r >> 2) + 4 * g];
        }
        #pragma unroll
        for (int ks = 0; ks < 8; ++ks) {
            int ad = el * 128 + 8 * ((2 * ks + g) ^ (el & 7));
            f16x8 bhi = *(const f16x8*)&Chi[ad];
            f16x8 blo = *(const f16x8*)&Clo[ad];
            a0 = __builtin_amdgcn_mfma_f32_32x32x16_f16(W[ks * 2 + 0], bhi, a0, 0, 0, 0);
            a1 = __builtin_amdgcn_mfma_f32_32x32x16_f16(W[ks * 2 + 1], bhi, a1, 0, 0, 0);
            a0 = __builtin_amdgcn_mfma_f32_32x32x16_f16(W[ks * 2 + 0], blo, a0, 0, 0, 0);
            a1 = __builtin_amdgcn_mfma_f32_32x32x16_f16(W[ks * 2 + 1], blo, a1, 0, 0, 0);
        }
        writeback(Nhi, Nlo, a0, a1);
    };

    midlayer(Wa, 128, Ha1, La1, Ha0, La0);   // L1 (w1): reads A1, writes A0
    __syncthreads();

    // prefetch w3 -> Wa (Wa free after L1; per-wave register dep guarantees order)
    #pragma unroll
    for (int ks = 0; ks < 8; ++ks)
        #pragma unroll
        for (int ft = 0; ft < 2; ++ft)
            Wa[ks * 2 + ft] = wsv[(((2 * 2 + fg) * 8 + ks) * 2 + ft) * 64 + lane];

    midlayer(Wb, 256, Ha0, La0, Ha1, La1);   // L2 (w2): reads A0, writes A1
    __syncthreads();
    midlayer(Wa, 384, Ha1, La1, Ha0, La0);   // L3 (w3): reads A1, writes A0
    __syncthreads();

    // ---- final layer 128 -> 2, 4 lanes per edge, atomic segment-sum ----
    {
        int e = tid >> 2, q = tid & 3;
        const float* w4l = &W4r[q * 260];
        float y0 = 0.0f, y1 = 0.0f;
        #pragma unroll
        for (int cc = 0; cc < 4; ++cc) {
            int c = 4 * q + cc;
            int ad = e * 128 + 8 * (c ^ (e & 7));
            f16x8 hv = *(const f16x8*)&Ha0[ad];
            f16x8 lv = *(const f16x8*)&La0[ad];
            #pragma unroll
            for (int i = 0; i < 8; ++i) {
                float x = (float)hv[i] + (float)lv[i];
                int k = 8 * c + i;
                y0 += x * w4l[2 * k];
                y1 += x * w4l[2 * k + 1];
            }
        }
        y0 += __shfl_xor(y0, 1); y0 += __shfl_xor(y0, 2);
        y1 += __shfl_xor(y1, 1); y1 += __shfl_xor(y1, 2);
        int eG = e0 + e;
        if (q == 0 && eG < nEdges) {
            int d = ei[eG];
            atomicAdd(&out[2 * d],     y0 + b4[0]);
            atomicAdd(&out[2 * d + 1], y1 + b4[1]);
        }
    }
}

extern "C" void kernel_launch(void* const* d_in, const int* in_sizes, int n_in,
                              void* d_out, int out_size, void* d_ws, size_t ws_size,
                              hipStream_t stream) {
    const float* pos   = (const float*)d_in[0];
    const float* vel   = (const float*)d_in[1];
    const float* a     = (const float*)d_in[2];
    const float* vnorm = (const float*)d_in[3];
    const float* w0    = (const float*)d_in[4];
    const float* b0    = (const float*)d_in[5];
    const float* w1    = (const float*)d_in[6];
    const float* b1    = (const float*)d_in[7];
    const float* w2    = (const float*)d_in[8];
    const float* b2    = (const float*)d_in[9];
    const float* w3    = (const float*)d_in[10];
    const float* b3    = (const float*)d_in[11];
    const float* w4    = (const float*)d_in[12];
    const float* b4    = (const float*)d_in[13];
    const int*   ei    = (const int*)d_in[14];
    const int*   did   = (const int*)d_in[15];
    float* out = (float*)d_out;
    f16* ws = (f16*)d_ws;

    int nEdges = in_sizes[14] / 2;   // 800000
    int nNodes = in_sizes[0] / 2;    // 50000

    hipLaunchKernelGGL(zero_f32, dim3((out_size + 255) / 256), dim3(256), 0, stream,
                       out, out_size);
    hipLaunchKernelGGL(prep_weights, dim3(200), dim3(256), 0, stream, w1, w2, w3, w0, ws);
    int ntiles = (nEdges + 63) / 64;
    hipLaunchKernelGGL(gnn_mfma, dim3(ntiles), dim3(256), 0, stream,
                       pos, vel, a, vnorm, b0, b1, b2, b3, w4, b4, ei, did, ws, out,
                       nNodes, nEdges);
}

// Round 4
// 154.990 us; speedup vs baseline: 7.4161x; 1.3860x over previous
//
#include <hip/hip_runtime.h>
#include <math.h>

typedef _Float16 f16;
typedef f16 f16x8 __attribute__((ext_vector_type(8)));
typedef f16 f16x4 __attribute__((ext_vector_type(4)));
typedef float f32x16 __attribute__((ext_vector_type(16)));

// ws layout (f16 units):
//  mid W (w1,w2,w3) per-wave frags, single f16:
//    flat = (((l*2+fg)*8+ks)*2+ft)*512 + (32*g+ln)*8 + i
//    (f = 64*fg+32*ft+ln, k = 16*ks+8*g+i)
//  W0 frags at 49152 (2048 f16): ((fg*2+ft)*2+g)*256 + ln*8 + i (k<16, pad 0)
//  packed bias (f32) at f16-offset 53248: 512 floats:
//    idx = ((l*2+fg)*2+ft)*32 + g*16 + 4*j + m = b_l[64fg+32ft+8j+4g+m], l=0..3
#define WS_W0 49152
#define WS_BIAS 53248

__global__ void zero_f32(float* __restrict__ p, int n) {
    int i = blockIdx.x * blockDim.x + threadIdx.x;
    if (i < n) p[i] = 0.0f;
}

__global__ void prep_weights(const float* __restrict__ w1, const float* __restrict__ w2,
                             const float* __restrict__ w3, const float* __restrict__ w0,
                             const float* __restrict__ b0, const float* __restrict__ b1,
                             const float* __restrict__ b2, const float* __restrict__ b3,
                             f16* __restrict__ ws) {
    int t = blockIdx.x * 256 + threadIdx.x;
    if (t < 49152) {
        int l = t >> 14;
        int r = t & 16383;
        int k = r >> 7, f = r & 127;
        const float* w = (l == 0) ? w1 : (l == 1) ? w2 : w3;
        float v = w[k * 128 + f];
        int fg = f >> 6, ft = (f >> 5) & 1, ln = f & 31;
        int ks = k >> 4, g = (k >> 3) & 1, i = k & 7;
        ws[(((l * 2 + fg) * 8 + ks) * 2 + ft) * 512 + (32 * g + ln) * 8 + i] = (f16)v;
    } else if (t < 51200) {
        int r = t - 49152;
        int k = r >> 7, f = r & 127;   // k 0..15
        float v = (k < 9) ? w0[k * 128 + f] : 0.0f;
        int fg = f >> 6, ft = (f >> 5) & 1, ln = f & 31;
        int g = (k >> 3) & 1, i = k & 7;
        ws[WS_W0 + ((fg * 2 + ft) * 2 + g) * 256 + ln * 8 + i] = (f16)v;
    } else if (t < 51712) {
        int b = t - 51200;             // 0..511
        int l = b >> 7, r = b & 127;
        int fg = r >> 6, ft = (r >> 5) & 1, g = (r >> 4) & 1, j = (r >> 2) & 3, m = r & 3;
        const float* bl = (l == 0) ? b0 : (l == 1) ? b1 : (l == 2) ? b2 : b3;
        ((float*)(ws + WS_BIAS))[b] = bl[64 * fg + 32 * ft + 8 * j + 4 * g + m];
    }
}

__launch_bounds__(256, 4)
__global__ void gnn_mfma(const float* __restrict__ pos, const float* __restrict__ vel,
                         const float* __restrict__ a, const float* __restrict__ vnorm,
                         const float* __restrict__ w4, const float* __restrict__ b4,
                         const int* __restrict__ ei, const int* __restrict__ did,
                         const f16* __restrict__ ws, float* __restrict__ out,
                         int nNodes, int nEdges)
{
    __shared__ __align__(16) f16 A0[8192], A1[8192];   // 2 x 16 KB, chunk-swizzled
    __shared__ float W4r[4 * 260];                     // 4 q-replicas of w4

    const int tid = threadIdx.x;
    const int lane = tid & 63;
    const int wid = tid >> 6;
    const int eg = wid & 1, fg = wid >> 1;
    const int g = lane >> 5, ln = lane & 31;
    const int el = 32 * eg + ln;
    const int e0 = blockIdx.x * 64;

    const f16x8* wsv = (const f16x8*)ws;
    const float* wsb = (const float*)(ws + WS_BIAS);

    // W frags for current mid layer (single buffer, SSA-renamed on refill)
    f16x8 W[16];
    #pragma unroll
    for (int ks = 0; ks < 8; ++ks)
        #pragma unroll
        for (int ft = 0; ft < 2; ++ft)
            W[ks * 2 + ft] = wsv[(((0 * 2 + fg) * 8 + ks) * 2 + ft) * 64 + lane];

    f16x8 w0f0 = wsv[WS_W0 / 8 + ((fg * 2 + 0) * 2 + g) * 32 + ln];
    f16x8 w0f1 = wsv[WS_W0 / 8 + ((fg * 2 + 1) * 2 + g) * 32 + ln];

    // replicated w4 -> LDS
    {
        int q = tid >> 6, r = tid & 63;
        #pragma unroll
        for (int it = 0; it < 4; ++it)
            W4r[q * 260 + r + 64 * it] = w4[r + 64 * it];
    }

    // ---- gather: 9 features, hi in chunks 0-1, lo in chunks 2-3 ----
    if (tid < 64) {
        int e = e0 + tid;
        int d = 0, s = 0;
        if (e < nEdges) { d = ei[e]; s = ei[nEdges + e]; }
        float2 pd = ((const float2*)pos)[d];
        float2 ps = ((const float2*)pos)[s];
        float2 vd = ((const float2*)vel)[d];
        float2 vs = ((const float2*)vel)[s];
        const float2* emb = (const float2*)(a + (size_t)did[0] * (size_t)nNodes * 2);
        float2 ae = emb[d];
        float invn = 1.0f / vnorm[0];
        float fx[9];
        fx[0] = (ps.x - pd.x) / 0.1f;
        fx[1] = (ps.y - pd.y) / 0.1f;
        fx[2] = sqrtf(fx[0] * fx[0] + fx[1] * fx[1]);
        fx[3] = vd.x * invn; fx[4] = vd.y * invn;
        fx[5] = vs.x * invn; fx[6] = vs.y * invn;
        fx[7] = ae.x; fx[8] = ae.y;
        f16x8 h0, l0, h1, l1;
        #pragma unroll
        for (int i = 0; i < 8; ++i) {
            f16 h = (f16)fx[i];
            h0[i] = h; l0[i] = (f16)(fx[i] - (float)h);
            h1[i] = (f16)0; l1[i] = (f16)0;
        }
        f16 h8 = (f16)fx[8];
        h1[0] = h8; l1[0] = (f16)(fx[8] - (float)h8);
        int er = tid;
        *(f16x8*)&A0[er * 128 + 8 * (0 ^ (er & 7))] = h0;
        *(f16x8*)&A0[er * 128 + 8 * (1 ^ (er & 7))] = h1;
        *(f16x8*)&A0[er * 128 + 8 * (2 ^ (er & 7))] = l0;
        *(f16x8*)&A0[er * 128 + 8 * (3 ^ (er & 7))] = l1;
    }
    __syncthreads();

    f32x16 acc0, acc1;

    auto bias_init = [&](int l) {
        #pragma unroll
        for (int ft = 0; ft < 2; ++ft) {
            const float* bp = wsb + ((l * 2 + fg) * 2 + ft) * 32 + g * 16;
            #pragma unroll
            for (int j = 0; j < 4; ++j) {
                float4 bv = *(const float4*)(bp + 4 * j);
                if (ft) { acc1[4*j] = bv.x; acc1[4*j+1] = bv.y; acc1[4*j+2] = bv.z; acc1[4*j+3] = bv.w; }
                else    { acc0[4*j] = bv.x; acc0[4*j+1] = bv.y; acc0[4*j+2] = bv.z; acc0[4*j+3] = bv.w; }
            }
        }
    };

    auto writeback = [&](f16* N) {
        #pragma unroll
        for (int ft = 0; ft < 2; ++ft)
            #pragma unroll
            for (int j = 0; j < 4; ++j) {
                f16x4 hv;
                #pragma unroll
                for (int m = 0; m < 4; ++m)
                    hv[m] = (f16)fmaxf((ft ? acc1 : acc0)[4 * j + m], 0.0f);
                int c = 8 * fg + 4 * ft + j;
                *(f16x4*)&N[el * 128 + 8 * (c ^ (el & 7)) + 4 * g] = hv;
            }
    };

    // ---- layer 0: K=16, input hi/lo ----
    bias_init(0);
    {
        f16x8 bhi = *(const f16x8*)&A0[el * 128 + 8 * (g ^ (el & 7))];
        f16x8 blo = *(const f16x8*)&A0[el * 128 + 8 * ((2 + g) ^ (el & 7))];
        acc0 = __builtin_amdgcn_mfma_f32_32x32x16_f16(w0f0, bhi, acc0, 0, 0, 0);
        acc1 = __builtin_amdgcn_mfma_f32_32x32x16_f16(w0f1, bhi, acc1, 0, 0, 0);
        acc0 = __builtin_amdgcn_mfma_f32_32x32x16_f16(w0f0, blo, acc0, 0, 0, 0);
        acc1 = __builtin_amdgcn_mfma_f32_32x32x16_f16(w0f1, blo, acc1, 0, 0, 0);
    }
    writeback(A1);
    __syncthreads();

    // ---- mid layers: K=128, W from regs, B single-f16 from LDS ----
    auto midlayer = [&](int l, const f16* S) {
        bias_init(l + 1);
        #pragma unroll
        for (int ks = 0; ks < 8; ++ks) {
            f16x8 b = *(const f16x8*)&S[el * 128 + 8 * ((2 * ks + g) ^ (el & 7))];
            acc0 = __builtin_amdgcn_mfma_f32_32x32x16_f16(W[ks * 2 + 0], b, acc0, 0, 0, 0);
            acc1 = __builtin_amdgcn_mfma_f32_32x32x16_f16(W[ks * 2 + 1], b, acc1, 0, 0, 0);
        }
    };

    midlayer(0, A1);                   // w1: A1 -> A0
    #pragma unroll
    for (int ks = 0; ks < 8; ++ks)     // prefetch w2 (issue early, consume next layer)
        #pragma unroll
        for (int ft = 0; ft < 2; ++ft)
            W[ks * 2 + ft] = wsv[(((1 * 2 + fg) * 8 + ks) * 2 + ft) * 64 + lane];
    writeback(A0);
    __syncthreads();

    midlayer(1, A0);                   // w2: A0 -> A1
    #pragma unroll
    for (int ks = 0; ks < 8; ++ks)     // prefetch w3
        #pragma unroll
        for (int ft = 0; ft < 2; ++ft)
            W[ks * 2 + ft] = wsv[(((2 * 2 + fg) * 8 + ks) * 2 + ft) * 64 + lane];
    writeback(A1);
    __syncthreads();

    midlayer(2, A1);                   // w3: A1 -> A0
    writeback(A0);
    __syncthreads();

    // ---- final layer 128 -> 2, 4 lanes per edge, atomic segment-sum ----
    {
        int e = tid >> 2, q = tid & 3;
        const float* w4l = &W4r[q * 260];
        float y0 = 0.0f, y1 = 0.0f;
        #pragma unroll
        for (int cc = 0; cc < 4; ++cc) {
            int c = 4 * q + cc;
            f16x8 hv = *(const f16x8*)&A0[e * 128 + 8 * (c ^ (e & 7))];
            #pragma unroll
            for (int i = 0; i < 8; ++i) {
                float x = (float)hv[i];
                int k = 8 * c + i;
                y0 += x * w4l[2 * k];
                y1 += x * w4l[2 * k + 1];
            }
        }
        y0 += __shfl_xor(y0, 1); y0 += __shfl_xor(y0, 2);
        y1 += __shfl_xor(y1, 1); y1 += __shfl_xor(y1, 2);
        int eG = e0 + e;
        if (q == 0 && eG < nEdges) {
            int d = ei[eG];
            atomicAdd(&out[2 * d],     y0 + b4[0]);
            atomicAdd(&out[2 * d + 1], y1 + b4[1]);
        }
    }
}

extern "C" void kernel_launch(void* const* d_in, const int* in_sizes, int n_in,
                              void* d_out, int out_size, void* d_ws, size_t ws_size,
                              hipStream_t stream) {
    const float* pos   = (const float*)d_in[0];
    const float* vel   = (const float*)d_in[1];
    const float* a     = (const float*)d_in[2];
    const float* vnorm = (const float*)d_in[3];
    const float* w0    = (const float*)d_in[4];
    const float* b0    = (const float*)d_in[5];
    const float* w1    = (const float*)d_in[6];
    const float* b1    = (const float*)d_in[7];
    const float* w2    = (const float*)d_in[8];
    const float* b2    = (const float*)d_in[9];
    const float* w3    = (const float*)d_in[10];
    const float* b3    = (const float*)d_in[11];
    const float* w4    = (const float*)d_in[12];
    const float* b4    = (const float*)d_in[13];
    const int*   ei    = (const int*)d_in[14];
    const int*   did   = (const int*)d_in[15];
    float* out = (float*)d_out;
    f16* ws = (f16*)d_ws;

    int nEdges = in_sizes[14] / 2;   // 800000
    int nNodes = in_sizes[0] / 2;    // 50000

    hipLaunchKernelGGL(zero_f32, dim3((out_size + 255) / 256), dim3(256), 0, stream,
                       out, out_size);
    hipLaunchKernelGGL(prep_weights, dim3(202), dim3(256), 0, stream,
                       w1, w2, w3, w0, b0, b1, b2, b3, ws);
    int ntiles = (nEdges + 63) / 64;
    hipLaunchKernelGGL(gnn_mfma, dim3(ntiles), dim3(256), 0, stream,
                       pos, vel, a, vnorm, w4, b4, ei, did, ws, out,
                       nNodes, nEdges);
}